// Round 1
// baseline (32.522 us; speedup 1.0000x reference)
//
#include <hip/hip_runtime.h>
#include <hip/hip_bf16.h>

#define NO 32
#define HH 64
#define WW 1024
#define LL (HH * WW)
#define BB 8

__global__ __launch_bounds__(256) void pnc_kernel(
    const float* __restrict__ x, const float* __restrict__ X,
    const float* __restrict__ A, const float* __restrict__ E,
    const float* __restrict__ M, const float* __restrict__ cw,
    const float* __restrict__ cb, float* __restrict__ out)
{
    __shared__ float sw[NO * 4];
    __shared__ float sb[NO];
    const int tid = threadIdx.x;
    if (tid < NO * 4) sw[tid] = cw[tid];
    if (tid < NO) sb[tid] = cb[tid];
    __syncthreads();

    const int gid = blockIdx.x * 256 + tid;     // 0 .. B*L-1
    const int b = gid >> 16;                    // / 65536
    const int l = gid & (LL - 1);
    const int h = l >> 10;
    const int w = l & 1023;

    const float* xb = x + b * LL;
    const float* Xb = X + b * LL;
    const float* Ab = A + b * LL;
    const float* Eb = E + b * LL;
    const float* Mb = M + b * LL;

    const float xc = xb[l];
    const float Xc = Xb[l];
    const float Ac = Ab[l];
    const float Ec = Eb[l];
    const float Mc = Mb[l];

    float t0[9], t1[9], t2[9], t3[9], mk[9];

    #pragma unroll
    for (int ki = 0; ki < 3; ++ki) {
        #pragma unroll
        for (int kj = 0; kj < 3; ++kj) {
            const int k = ki * 3 + kj;
            const int hh = h + ki - 1;
            const int ww = w + kj - 1;
            if (k == 4) {
                // center: Ad = Ed = 0 -> cA=cE=1, sA=sE=0
                mk[4] = Mc * Mc;
                t0[4] = xc;
                t1[4] = xc - Xc;
                t2[4] = 0.f;
                t3[4] = 0.f;
            } else if (hh >= 0 && hh < HH && ww >= 0 && ww < WW) {
                const int ll = hh * WW + ww;
                const float ux = xb[ll];
                const float uA = Ab[ll];
                const float uE = Eb[ll];
                const float uM = Mb[ll];
                mk[k] = Mc * uM;
                float sA, cA, sE, cE;
                __sincosf(uA - Ac, &sA, &cA);
                __sincosf(uE - Ec, &sE, &cE);
                const float xcA = ux * cA;
                t0[k] = ux;
                t1[k] = __fmaf_rn(xcA, cE, -Xc);
                t2[k] = xcA * sE;
                t3[k] = ux * sA;
            } else {
                // out of bounds: uM = 0 -> masked to zero regardless of t
                mk[k] = 0.f;
                t0[k] = 0.f; t1[k] = 0.f; t2[k] = 0.f; t3[k] = 0.f;
            }
        }
    }

    float* ob = out + b * (NO * LL) + l;

    #pragma unroll 8
    for (int o = 0; o < NO; ++o) {
        const float4 wv = *reinterpret_cast<const float4*>(&sw[o * 4]);
        const float bo = sb[o];
        float v[9];
        #pragma unroll
        for (int k = 0; k < 9; ++k) {
            float s = __fmaf_rn(wv.x, t0[k], bo);
            s = __fmaf_rn(wv.y, t1[k], s);
            s = __fmaf_rn(wv.z, t2[k], s);
            s = __fmaf_rn(wv.w, t3[k], s);
            v[k] = s * mk[k];
        }
        // max over 9 (max3-fusable tree)
        float m0 = fmaxf(fmaxf(v[0], v[1]), v[2]);
        float m1 = fmaxf(fmaxf(v[3], v[4]), v[5]);
        float m2 = fmaxf(fmaxf(v[6], v[7]), v[8]);
        ob[o * LL] = fmaxf(fmaxf(m0, m1), m2);
    }
}

extern "C" void kernel_launch(void* const* d_in, const int* in_sizes, int n_in,
                              void* d_out, int out_size, void* d_ws, size_t ws_size,
                              hipStream_t stream) {
    const float* x  = (const float*)d_in[0];
    const float* X  = (const float*)d_in[1];
    const float* A  = (const float*)d_in[2];
    const float* E  = (const float*)d_in[3];
    const float* M  = (const float*)d_in[4];
    const float* cw = (const float*)d_in[5];
    const float* cb = (const float*)d_in[6];
    float* out = (float*)d_out;

    const int total = BB * LL;               // 524288 threads, 1 pixel each
    pnc_kernel<<<total / 256, 256, 0, stream>>>(x, X, A, E, M, cw, cb, out);
}

// Round 3
// 29.431 us; speedup vs baseline: 1.1050x; 1.1050x over previous
//
#include <hip/hip_runtime.h>
#include <hip/hip_bf16.h>

#define NO 32
#define HH 64
#define WW 1024
#define LL (HH * WW)
#define BB 8

typedef _Float16 h2 __attribute__((ext_vector_type(2)));

__device__ __forceinline__ h2 pk(float a, float b) {
    return __builtin_bit_cast(h2, __builtin_amdgcn_cvt_pkrtz(a, b));
}
__device__ __forceinline__ h2 fma2(h2 a, h2 b, h2 c) {
    return __builtin_elementwise_fma(a, b, c);
}
__device__ __forceinline__ h2 max2(h2 a, h2 b) {
    return __builtin_elementwise_max(a, b);
}
__device__ __forceinline__ h2 uash2(unsigned u) {
    return __builtin_bit_cast(h2, u);
}
__device__ __forceinline__ unsigned h2asu(h2 h) {
    return __builtin_bit_cast(unsigned, h);
}

__global__ __launch_bounds__(256, 8) void pnc_kernel(
    const float* __restrict__ x, const float* __restrict__ X,
    const float* __restrict__ A, const float* __restrict__ E,
    const float* __restrict__ M, const float* __restrict__ cw,
    const float* __restrict__ cb, float* __restrict__ out)
{
    // LDS: sincos tiles (f16x2 [sin,cos]) for A and E over 3 rows x 258 cols halo
    __shared__ unsigned tA[3 * 258];
    __shared__ unsigned tE[3 * 258];
    __shared__ uint4    swp[NO];   // duplicated f16x2 weight pairs [w,w] x4
    __shared__ unsigned sbp[NO];   // duplicated f16x2 bias pair
    __shared__ float4   swc[NO];   // f32 (w0, w1, b, 0) for center tap

    const int tid = threadIdx.x;
    const int bi  = blockIdx.x;
    const int b   = bi >> 8;           // 256 blocks per image (64 h x 4 col-quarters)
    const int h   = (bi >> 2) & 63;
    const int w0q = (bi & 3) << 8;
    const int w   = w0q + tid;
    const int l   = (h << 10) + w;

    const float* xb = x + b * LL;
    const float* Xb = X + b * LL;
    const float* Ab = A + b * LL;
    const float* Eb = E + b * LL;
    const float* Mb = M + b * LL;

    // ---- weight staging ----
    if (tid < NO) {
        const int o = tid;
        const float w0 = cw[o * 4 + 0], w1 = cw[o * 4 + 1];
        const float w2 = cw[o * 4 + 2], w3 = cw[o * 4 + 3];
        const float bo = cb[o];
        swp[o] = make_uint4(h2asu(pk(w0, w0)), h2asu(pk(w1, w1)),
                            h2asu(pk(w2, w2)), h2asu(pk(w3, w3)));
        sbp[o] = h2asu(pk(bo, bo));
        swc[o] = make_float4(w0, w1, bo, 0.f);
    }

    // ---- sincos tile fill: 3 rows x 258 cols of raw A, E angles ----
    for (int s = tid; s < 3 * 258; s += 256) {
        const int r = s / 258;
        const int c = s - r * 258;
        int gh = h - 1 + r; gh = min(max(gh, 0), HH - 1);
        int gw = w0q - 1 + c; gw = min(max(gw, 0), WW - 1);
        const int gl = (gh << 10) + gw;
        const float a = Ab[gl], e = Eb[gl];
        float sa, ca, se, ce;
        __sincosf(a, &sa, &ca);
        __sincosf(e, &se, &ce);
        tA[s] = h2asu(pk(sa, ca));
        tE[s] = h2asu(pk(se, ce));
    }
    __syncthreads();

    // ---- center values ----
    const float xc = xb[l];
    const float Xc = Xb[l];
    const float Mc = Mb[l];
    const int   cl = tid + 1;
    const h2 cpA = uash2(tA[258 + cl]);
    const h2 cpE = uash2(tE[258 + cl]);
    const float sAc = (float)cpA.x, cAc = (float)cpA.y;
    const float sEc = (float)cpE.x, cEc = (float)cpE.y;

    // ---- 8 off-center taps -> 4 packed f16x2 pairs ----
    // tap order (di,dj): (-1,-1)(-1,0)(-1,1)(0,-1)(0,1)(1,-1)(1,0)(1,1)
    const int DI[8] = {-1, -1, -1, 0, 0, 1, 1, 1};
    const int DJ[8] = {-1,  0,  1, -1, 1, -1, 0, 1};

    h2 T0[4], T1[4], T2[4], T3[4], MK[4];

    #pragma unroll
    for (int p = 0; p < 4; ++p) {
        float f0[2], f1[2], f2[2], f3[2], mk[2];
        #pragma unroll
        for (int q = 0; q < 2; ++q) {
            const int k  = 2 * p + q;
            const int di = DI[k], dj = DJ[k];
            const int hh = h + di, ww = w + dj;
            const bool valid = ((unsigned)hh < (unsigned)HH) &
                               ((unsigned)ww < (unsigned)WW);
            const int ll = (l + di * 1024 + dj) & (LL - 1);  // clamped-safe addr
            const float ux = xb[ll];
            const float uM = Mb[ll];
            mk[q] = valid ? uM : 0.f;
            const int ts = (di + 1) * 258 + cl + dj;
            const h2 pa = uash2(tA[ts]);
            const h2 pe = uash2(tE[ts]);
            const float sAu = (float)pa.x, cAu = (float)pa.y;
            const float sEu = (float)pe.x, cEu = (float)pe.y;
            // rotation: angle difference identities
            const float cA = __fmaf_rn(cAu, cAc, sAu * sAc);
            const float sA = __fmaf_rn(sAu, cAc, -(cAu * sAc));
            const float cE = __fmaf_rn(cEu, cEc, sEu * sEc);
            const float sE = __fmaf_rn(sEu, cEc, -(cEu * sEc));
            const float xcA = ux * cA;
            f0[q] = ux;
            f1[q] = __fmaf_rn(xcA, cE, -Xc);
            f2[q] = xcA * sE;
            f3[q] = ux * sA;
        }
        T0[p] = pk(f0[0], f0[1]);
        T1[p] = pk(f1[0], f1[1]);
        T2[p] = pk(f2[0], f2[1]);
        T3[p] = pk(f3[0], f3[1]);
        MK[p] = pk(mk[0], mk[1]);
    }

    const float xmX = xc - Xc;
    float* ob = out + b * (NO * LL) + l;

    #pragma unroll 8
    for (int o = 0; o < NO; ++o) {
        const uint4 wp = swp[o];
        const h2 w0 = uash2(wp.x), w1 = uash2(wp.y);
        const h2 w2 = uash2(wp.z), w3 = uash2(wp.w);
        const h2 wb = uash2(sbp[o]);
        h2 m2;
        #pragma unroll
        for (int p = 0; p < 4; ++p) {
            h2 s = fma2(w0, T0[p], wb);
            s = fma2(w1, T1[p], s);
            s = fma2(w2, T2[p], s);
            s = fma2(w3, T3[p], s);
            s = s * MK[p];
            m2 = (p == 0) ? s : max2(m2, s);
        }
        // center tap in f32 (t2=t3=0, mask = Mc)
        const float4 wc = swc[o];
        const float sc = __fmaf_rn(wc.x, xc, __fmaf_rn(wc.y, xmX, wc.z));
        const float vc = sc * Mc;
        const float m  = fmaxf(fmaxf((float)m2.x, (float)m2.y), vc);
        ob[o * LL] = m * Mc;
    }
}

extern "C" void kernel_launch(void* const* d_in, const int* in_sizes, int n_in,
                              void* d_out, int out_size, void* d_ws, size_t ws_size,
                              hipStream_t stream) {
    const float* x  = (const float*)d_in[0];
    const float* X  = (const float*)d_in[1];
    const float* A  = (const float*)d_in[2];
    const float* E  = (const float*)d_in[3];
    const float* M  = (const float*)d_in[4];
    const float* cw = (const float*)d_in[5];
    const float* cb = (const float*)d_in[6];
    float* out = (float*)d_out;

    pnc_kernel<<<BB * 64 * 4, 256, 0, stream>>>(x, X, A, E, M, cw, cb, out);
}